// Round 1
// baseline (1412.773 us; speedup 1.0000x reference)
//
#include <hip/hip_runtime.h>
#include <hip/hip_bf16.h>

typedef __bf16 bf16x8 __attribute__((ext_vector_type(8)));
typedef float  f32x4  __attribute__((ext_vector_type(4)));

#define MFMA(a, b, c) __builtin_amdgcn_mfma_f32_16x16x32_bf16((a), (b), (c), 0, 0, 0)

typedef __attribute__((address_space(1))) void* as1_vp;
typedef __attribute__((address_space(3))) void* as3_vp;

// async global->LDS, 16B per lane; LDS dest is wave-uniform base + lane*16
__device__ __forceinline__ void g2lds16(const void* g, void* lds) {
  __builtin_amdgcn_global_load_lds((as1_vp)(unsigned long long)g,
                                   (as3_vp)(unsigned int)(unsigned long long)lds,
                                   16, 0, 0);
}

// ---------------------------------------------------------------- convert
__global__ void cvt_f32_bf16(const float* __restrict__ in,
                             __hip_bfloat16* __restrict__ out, int n4) {
  int i = blockIdx.x * blockDim.x + threadIdx.x;
  if (i >= n4) return;
  float4 v = ((const float4*)in)[i];
  ushort4 u;
  u.x = __builtin_bit_cast(unsigned short, __float2bfloat16(v.x));
  u.y = __builtin_bit_cast(unsigned short, __float2bfloat16(v.y));
  u.z = __builtin_bit_cast(unsigned short, __float2bfloat16(v.z));
  u.w = __builtin_bit_cast(unsigned short, __float2bfloat16(v.w));
  ((ushort4*)out)[i] = u;
}

// ---------------------------------------------------------------- rope (in-place)
// x layout [B][S][H][HD]; pair i -> elements 2i, 2i+1.  hshift = log2(H), S=2048.
__global__ void rope_inplace(__hip_bfloat16* __restrict__ x, const float* __restrict__ fc,
                             const int* __restrict__ startpos, int hshift, long npairs) {
  long i = (long)blockIdx.x * blockDim.x + threadIdx.x;
  if (i >= npairs) return;
  int  j  = (int)(i & 63);
  long r  = i >> 6;
  long bs = r >> hshift;
  int  s  = (int)(bs & 2047);
  int  sp = startpos[0] + s;
  float c  = fc[(sp << 7) + (j << 1)];
  float sn = fc[(sp << 7) + (j << 1) + 1];
  float xr = __bfloat162float(x[2 * i]);
  float xi = __bfloat162float(x[2 * i + 1]);
  x[2 * i]     = __float2bfloat16(xr * c - xi * sn);
  x[2 * i + 1] = __float2bfloat16(xr * sn + xi * c);
}

// ---------------------------------------------------------------- batched 2D transpose
// in: [b][R][C] -> out: [b][C][R]
__global__ void transpose2d_bf16(const __hip_bfloat16* __restrict__ in,
                                 __hip_bfloat16* __restrict__ out, int R, int C) {
  __shared__ __hip_bfloat16 tile[32][33];
  int b = blockIdx.z;
  const __hip_bfloat16* ib = in + (long)b * R * C;
  __hip_bfloat16* ob = out + (long)b * R * C;
  int c0 = blockIdx.x * 32, r0 = blockIdx.y * 32;
#pragma unroll
  for (int rr = threadIdx.y; rr < 32; rr += 8)
    tile[rr][threadIdx.x] = ib[(long)(r0 + rr) * C + c0 + threadIdx.x];
  __syncthreads();
#pragma unroll
  for (int rr = threadIdx.y; rr < 32; rr += 8)
    ob[(long)(c0 + rr) * R + r0 + threadIdx.x] = tile[threadIdx.x][rr];
}

// ---------------------------------------------------------------- GEMM  C = A * W^T + bias
// A: MxK bf16 row-major, W: NxK bf16 row-major. 128x128 tile, BK=32, 256 thr.
template <int OUT_F32>
__global__ void __launch_bounds__(256) gemm_bt(const __hip_bfloat16* __restrict__ A,
                                               const __hip_bfloat16* __restrict__ W,
                                               const float* __restrict__ bias,
                                               void* __restrict__ Cout,
                                               int M, int N, int K) {
  __shared__ __align__(16) char As[8192];
  __shared__ __align__(16) char Bs[8192];
  const int t = threadIdx.x, w = t >> 6, l = t & 63, quad = l >> 4, lan = l & 15;
  const int bm = blockIdx.y << 7, bn = blockIdx.x << 7;
  const int wr = (w >> 1) << 6, wc = (w & 1) << 6;
  f32x4 acc[4][4] = {};

  const char* Ag0 = (const char*)(A + (long)(bm + (w << 4) + (l >> 2)) * K) + (l & 3) * 16;
  const char* Ag1 = (const char*)(A + (long)(bm + ((w + 4) << 4) + (l >> 2)) * K) + (l & 3) * 16;
  const char* Bg0 = (const char*)(W + (long)(bn + (w << 4) + (l >> 2)) * K) + (l & 3) * 16;
  const char* Bg1 = (const char*)(W + (long)(bn + ((w + 4) << 4) + (l >> 2)) * K) + (l & 3) * 16;
  char* AsW0 = As + (w << 10);
  char* AsW1 = As + ((w + 4) << 10);
  char* BsW0 = Bs + (w << 10);
  char* BsW1 = Bs + ((w + 4) << 10);

  for (int k0 = 0; k0 < K; k0 += 32) {
    g2lds16(Ag0 + k0 * 2, AsW0);
    g2lds16(Ag1 + k0 * 2, AsW1);
    g2lds16(Bg0 + k0 * 2, BsW0);
    g2lds16(Bg1 + k0 * 2, BsW1);
    __syncthreads();
    bf16x8 a[4], b[4];
#pragma unroll
    for (int i = 0; i < 4; i++)
      a[i] = *(const bf16x8*)(As + ((wr + (i << 4) + lan) << 6) + (quad << 4));
#pragma unroll
    for (int j = 0; j < 4; j++)
      b[j] = *(const bf16x8*)(Bs + ((wc + (j << 4) + lan) << 6) + (quad << 4));
#pragma unroll
    for (int i = 0; i < 4; i++)
#pragma unroll
      for (int j = 0; j < 4; j++)
        acc[i][j] = MFMA(a[i], b[j], acc[i][j]);
    __syncthreads();
  }

  float bv[4];
#pragma unroll
  for (int j = 0; j < 4; j++) bv[j] = bias[bn + wc + (j << 4) + lan];
#pragma unroll
  for (int i = 0; i < 4; i++) {
#pragma unroll
    for (int e = 0; e < 4; e++) {
      long row = bm + wr + (i << 4) + (quad << 2) + e;
#pragma unroll
      for (int j = 0; j < 4; j++) {
        float v = acc[i][j][e] + bv[j];
        long col = bn + wc + (j << 4) + lan;
        if (OUT_F32)
          ((float*)Cout)[row * N + col] = v;
        else
          ((__hip_bfloat16*)Cout)[row * N + col] = __float2bfloat16(v);
      }
    }
  }
}

// ---------------------------------------------------------------- flash attention
// Q: [B][S][32][128], K: [B][S][8][128], VT: [B][8][128][S], O: [B][S][32][128]
// grid (S/64, QH=32, B), 256 threads. causal.
__global__ void __launch_bounds__(256) flash_attn(const __hip_bfloat16* __restrict__ Q,
                                                  const __hip_bfloat16* __restrict__ Km,
                                                  const __hip_bfloat16* __restrict__ VT,
                                                  __hip_bfloat16* __restrict__ O, int S) {
  __shared__ __align__(16) char smem[49152];
  char* Qs = smem;          // 16KB; reused as P (64 x 72 bf16) after preload
  char* Ks = smem + 16384;  // 16KB: K tile [64][128]
  char* Vs = smem + 32768;  // 16KB: V^T tile [128][64]
  const int t = threadIdx.x, w = t >> 6, l = t & 63, quad = l >> 4, lan = l & 15;
  const int b = blockIdx.z, qh = blockIdx.y, kvh = qh >> 2;
  const int q0 = blockIdx.x << 6;
  const float cl = 0.08838834764831845f * 1.4426950408889634f;  // scale * log2(e)

  // stage Q tile (64 rows x 256B); inst i covers 4 rows, wave w does i = 4w..4w+3
#pragma unroll
  for (int ii = 0; ii < 4; ii++) {
    int i = (w << 2) + ii;
    int r = (i << 2) + (l >> 4);
    const char* g = (const char*)(Q + (((long)(b * S + q0 + r) * 32 + qh) << 7)) + (lan << 4);
    g2lds16(g, Qs + (i << 10));
  }
  __syncthreads();
  bf16x8 qf[4];
#pragma unroll
  for (int ks = 0; ks < 4; ks++)
    qf[ks] = *(const bf16x8*)(Qs + (((w << 4) + lan) << 8) + (ks << 6) + (quad << 4));

  f32x4 o[8] = {};
  float mrow[4] = {-__builtin_inff(), -__builtin_inff(), -__builtin_inff(), -__builtin_inff()};
  float lrow[4] = {0.f, 0.f, 0.f, 0.f};
  const int ntiles = blockIdx.x + 1;

  for (int kt = 0; kt < ntiles; kt++) {
    const int t0 = kt << 6;
    __syncthreads();  // previous P/V/K reads done before restage
    // stage K tile: rows t0..t0+63, 256B rows
#pragma unroll
    for (int ii = 0; ii < 4; ii++) {
      int i = (w << 2) + ii;
      int r = (i << 2) + (l >> 4);
      const char* g =
          (const char*)(Km + (((long)(b * S + t0 + r) * 8 + kvh) << 7)) + (lan << 4);
      g2lds16(g, Ks + (i << 10));
    }
    // stage V^T tile: rows d=0..127, 128B rows (64 t values)
#pragma unroll
    for (int ii = 0; ii < 4; ii++) {
      int i = (w << 2) + ii;
      int d = (i << 3) + (l >> 3);
      const char* g =
          (const char*)(VT + ((long)((b << 3) + kvh) * 128 + d) * S + t0) + ((l & 7) << 4);
      g2lds16(g, Vs + (i << 10));
    }
    __syncthreads();

    // S = Q K^T : wave strip rows w*16..+15, 4 n-tiles of 16 t-cols
    f32x4 sa[4] = {};
#pragma unroll
    for (int j = 0; j < 4; j++)
#pragma unroll
      for (int ks = 0; ks < 4; ks++) {
        bf16x8 kf = *(const bf16x8*)(Ks + (((j << 4) + lan) << 8) + (ks << 6) + (quad << 4));
        sa[j] = MFMA(qf[ks], kf, sa[j]);
      }

    if (kt == ntiles - 1) {  // diagonal tile: mask t > qrow
#pragma unroll
      for (int j = 0; j < 4; j++)
#pragma unroll
        for (int e = 0; e < 4; e++) {
          int tt = t0 + (j << 4) + lan;
          int qr = q0 + (w << 4) + (quad << 2) + e;
          if (tt > qr) sa[j][e] = -1e30f;
        }
    }

    // online softmax; row = quad*4+e lives in one quad (lanes vary over cols)
    float alpha[4];
#pragma unroll
    for (int e = 0; e < 4; e++) {
      float mx = fmaxf(fmaxf(sa[0][e], sa[1][e]), fmaxf(sa[2][e], sa[3][e]));
#pragma unroll
      for (int dd = 1; dd < 16; dd <<= 1) mx = fmaxf(mx, __shfl_xor(mx, dd, 16));
      float mn = fmaxf(mrow[e], mx);
      alpha[e] = exp2f((mrow[e] - mn) * cl);
      mrow[e] = mn;
    }
    float rsum[4] = {0.f, 0.f, 0.f, 0.f};
#pragma unroll
    for (int j = 0; j < 4; j++)
#pragma unroll
      for (int e = 0; e < 4; e++) {
        float p = exp2f((sa[j][e] - mrow[e]) * cl);
        rsum[e] += p;
        *(__hip_bfloat16*)(Qs + ((((w << 4) + (quad << 2) + e) * 72 + (j << 4) + lan) << 1)) =
            __float2bfloat16(p);
      }
#pragma unroll
    for (int e = 0; e < 4; e++) {
#pragma unroll
      for (int dd = 1; dd < 16; dd <<= 1) rsum[e] += __shfl_xor(rsum[e], dd, 16);
      lrow[e] = lrow[e] * alpha[e] + rsum[e];
    }
#pragma unroll
    for (int dt = 0; dt < 8; dt++)
#pragma unroll
      for (int e = 0; e < 4; e++) o[dt][e] *= alpha[e];

    __syncthreads();  // P writes visible (same wave, but keep ordering explicit)

    // O += P V : k-dim 64 (2 steps), 8 d-tiles
    bf16x8 pf[2];
#pragma unroll
    for (int ks = 0; ks < 2; ks++)
      pf[ks] = *(const bf16x8*)(Qs + ((w << 4) + lan) * 144 + (ks << 6) + (quad << 4));
#pragma unroll
    for (int dt = 0; dt < 8; dt++)
#pragma unroll
      for (int ks = 0; ks < 2; ks++) {
        bf16x8 vf = *(const bf16x8*)(Vs + (((dt << 4) + lan) << 7) + (ks << 6) + (quad << 4));
        o[dt] = MFMA(pf[ks], vf, o[dt]);
      }
  }

  float inv[4];
#pragma unroll
  for (int e = 0; e < 4; e++) inv[e] = 1.0f / lrow[e];
#pragma unroll
  for (int dt = 0; dt < 8; dt++)
#pragma unroll
    for (int e = 0; e < 4; e++) {
      long row = q0 + (w << 4) + (quad << 2) + e;
      O[(((long)b * S + row) * 32 + qh) * 128 + (dt << 4) + lan] =
          __float2bfloat16(o[dt][e] * inv[e]);
    }
}

// ---------------------------------------------------------------- launch
extern "C" void kernel_launch(void* const* d_in, const int* in_sizes, int n_in,
                              void* d_out, int out_size, void* d_ws, size_t ws_size,
                              hipStream_t stream) {
  const float* xs = (const float*)d_in[0];
  const int* startpos = (const int*)d_in[1];
  const float* fc = (const float*)d_in[2];
  const float* Wq = (const float*)d_in[3];
  const float* bq = (const float*)d_in[4];
  const float* Wk = (const float*)d_in[5];
  const float* bk = (const float*)d_in[6];
  const float* Wv = (const float*)d_in[7];
  const float* bv = (const float*)d_in[8];
  const float* Wo = (const float*)d_in[9];
  const float* bo = (const float*)d_in[10];
  float* out = (float*)d_out;
  char* ws = (char*)d_ws;

  __hip_bfloat16* Xb  = (__hip_bfloat16*)(ws);                  // 32MB  [4096][4096]
  __hip_bfloat16* Wqb = (__hip_bfloat16*)(ws + 33554432L);      // 32MB  (reused as Ctx)
  __hip_bfloat16* Wkb = (__hip_bfloat16*)(ws + 67108864L);      // 8MB
  __hip_bfloat16* Wvb = (__hip_bfloat16*)(ws + 75497472L);      // 8MB
  __hip_bfloat16* Qb  = (__hip_bfloat16*)(ws + 83886080L);      // 32MB
  __hip_bfloat16* Kb  = (__hip_bfloat16*)(ws + 117440512L);     // 8MB
  __hip_bfloat16* Vb  = (__hip_bfloat16*)(ws + 125829120L);     // 8MB
  __hip_bfloat16* VbT = (__hip_bfloat16*)(ws + 134217728L);     // 8MB
  __hip_bfloat16* Wob = (__hip_bfloat16*)(ws + 142606336L);     // 32MB  (total 168MB)
  __hip_bfloat16* Ctx = Wqb;                                    // reuse after Q-GEMM

  cvt_f32_bf16<<<16384, 256, 0, stream>>>(xs, Xb, 4194304);
  cvt_f32_bf16<<<16384, 256, 0, stream>>>(Wq, Wqb, 4194304);
  cvt_f32_bf16<<<4096, 256, 0, stream>>>(Wk, Wkb, 1048576);
  cvt_f32_bf16<<<4096, 256, 0, stream>>>(Wv, Wvb, 1048576);
  cvt_f32_bf16<<<16384, 256, 0, stream>>>(Wo, Wob, 4194304);

  gemm_bt<0><<<dim3(32, 32), 256, 0, stream>>>(Xb, Wqb, bq, Qb, 4096, 4096, 4096);
  gemm_bt<0><<<dim3(8, 32), 256, 0, stream>>>(Xb, Wkb, bk, Kb, 4096, 1024, 4096);
  gemm_bt<0><<<dim3(8, 32), 256, 0, stream>>>(Xb, Wvb, bv, Vb, 4096, 1024, 4096);

  rope_inplace<<<32768, 256, 0, stream>>>(Qb, fc, startpos, 5, 8388608L);
  rope_inplace<<<8192, 256, 0, stream>>>(Kb, fc, startpos, 3, 2097152L);
  transpose2d_bf16<<<dim3(32, 64, 2), dim3(32, 8), 0, stream>>>(Vb, VbT, 2048, 1024);

  flash_attn<<<dim3(32, 32, 2), 256, 0, stream>>>(Qb, Kb, VbT, Ctx, 2048);

  gemm_bt<1><<<dim3(32, 32), 256, 0, stream>>>(Ctx, Wob, bo, out, 4096, 4096, 4096);
}

// Round 2
// 977.265 us; speedup vs baseline: 1.4456x; 1.4456x over previous
//
#include <hip/hip_runtime.h>
#include <hip/hip_bf16.h>

typedef __bf16 bf16x8 __attribute__((ext_vector_type(8)));
typedef float  f32x4  __attribute__((ext_vector_type(4)));

#define MFMA(a, b, c) __builtin_amdgcn_mfma_f32_16x16x32_bf16((a), (b), (c), 0, 0, 0)

typedef __attribute__((address_space(1))) void* as1_vp;
typedef __attribute__((address_space(3))) void* as3_vp;

__device__ __forceinline__ void g2lds16(const void* g, void* lds) {
  __builtin_amdgcn_global_load_lds((as1_vp)(unsigned long long)g,
                                   (as3_vp)(unsigned int)(unsigned long long)lds,
                                   16, 0, 0);
}

__device__ __forceinline__ unsigned short bfbits(float x) {
  return __builtin_bit_cast(unsigned short, __float2bfloat16(x));
}

// ---------------------------------------------------------------- convert
__global__ void cvt_f32_bf16(const float* __restrict__ in,
                             __hip_bfloat16* __restrict__ out, int n4) {
  int i = blockIdx.x * blockDim.x + threadIdx.x;
  if (i >= n4) return;
  float4 v = ((const float4*)in)[i];
  ushort4 u;
  u.x = bfbits(v.x); u.y = bfbits(v.y); u.z = bfbits(v.z); u.w = bfbits(v.w);
  ((ushort4*)out)[i] = u;
}

// ---------------------------------------------------------------- bias concat (fp32)
__global__ void concat_bias(const float* __restrict__ bq, const float* __restrict__ bk,
                            const float* __restrict__ bv, float* __restrict__ out) {
  int i = blockIdx.x * 256 + threadIdx.x;  // 6144 total
  float v = (i < 4096) ? bq[i] : ((i < 5120) ? bk[i - 4096] : bv[i - 5120]);
  out[i] = v;
}

// ---------------------------------------------------------------- rope (in-place, pitch-aware)
// token row at x + token*pitch; pairs_per_token = 1<<wshift; pair wi -> elems 2wi,2wi+1
__global__ void rope_inplace(__hip_bfloat16* __restrict__ x, const float* __restrict__ fc,
                             const int* __restrict__ startpos, int pitch, int wshift,
                             long npairs) {
  long i = (long)blockIdx.x * blockDim.x + threadIdx.x;
  if (i >= npairs) return;
  int  wi    = (int)(i & ((1 << wshift) - 1));
  long token = i >> wshift;
  int  s  = (int)(token & 2047);
  int  j  = wi & 63;
  int  sp = startpos[0] + s;
  float c  = fc[(sp << 7) + (j << 1)];
  float sn = fc[(sp << 7) + (j << 1) + 1];
  long base = token * pitch + wi * 2;
  float xr = __bfloat162float(x[base]);
  float xi = __bfloat162float(x[base + 1]);
  x[base]     = __float2bfloat16(xr * c - xi * sn);
  x[base + 1] = __float2bfloat16(xr * sn + xi * c);
}

// ---------------------------------------------------------------- V transpose
// V lives in QKV at col 5120: [token][6144]. out VT: [(b*8+kvh)][128][2048]
__global__ void transpose_v(const __hip_bfloat16* __restrict__ QKV,
                            __hip_bfloat16* __restrict__ VT) {
  __shared__ __hip_bfloat16 tile[32][33];
  int z = blockIdx.z, b = z >> 3, kvh = z & 7;
  int s0 = blockIdx.x * 32, h0 = blockIdx.y * 32;
  int tx = threadIdx.x, ty = threadIdx.y;
#pragma unroll
  for (int ry = ty; ry < 32; ry += 8)
    tile[ry][tx] =
        QKV[(long)(b * 2048 + s0 + ry) * 6144 + 5120 + kvh * 128 + h0 + tx];
  __syncthreads();
#pragma unroll
  for (int ry = ty; ry < 32; ry += 8)
    VT[((long)z * 128 + h0 + ry) * 2048 + s0 + tx] = tile[tx][ry];
}

// ---------------------------------------------------------------- GEMM  C = A * W^T + bias
// A: MxK bf16 row-major, W: NxK bf16 row-major. 128x128 tile, BK=32, 256 thr.
template <int OUT_F32>
__global__ void __launch_bounds__(256) gemm_bt(const __hip_bfloat16* __restrict__ A,
                                               const __hip_bfloat16* __restrict__ W,
                                               const float* __restrict__ bias,
                                               void* __restrict__ Cout,
                                               int M, int N, int K) {
  __shared__ __align__(16) char As[8192];
  __shared__ __align__(16) char Bs[8192];
  const int t = threadIdx.x, w = t >> 6, l = t & 63, quad = l >> 4, lan = l & 15;
  const int bm = blockIdx.y << 7, bn = blockIdx.x << 7;
  const int wr = (w >> 1) << 6, wc = (w & 1) << 6;
  f32x4 acc[4][4] = {};

  const char* Ag0 = (const char*)(A + (long)(bm + (w << 4) + (l >> 2)) * K) + (l & 3) * 16;
  const char* Ag1 = (const char*)(A + (long)(bm + ((w + 4) << 4) + (l >> 2)) * K) + (l & 3) * 16;
  const char* Bg0 = (const char*)(W + (long)(bn + (w << 4) + (l >> 2)) * K) + (l & 3) * 16;
  const char* Bg1 = (const char*)(W + (long)(bn + ((w + 4) << 4) + (l >> 2)) * K) + (l & 3) * 16;
  char* AsW0 = As + (w << 10);
  char* AsW1 = As + ((w + 4) << 10);
  char* BsW0 = Bs + (w << 10);
  char* BsW1 = Bs + ((w + 4) << 10);

  for (int k0 = 0; k0 < K; k0 += 32) {
    g2lds16(Ag0 + k0 * 2, AsW0);
    g2lds16(Ag1 + k0 * 2, AsW1);
    g2lds16(Bg0 + k0 * 2, BsW0);
    g2lds16(Bg1 + k0 * 2, BsW1);
    __syncthreads();
    bf16x8 a[4], b[4];
#pragma unroll
    for (int i = 0; i < 4; i++)
      a[i] = *(const bf16x8*)(As + ((wr + (i << 4) + lan) << 6) + (quad << 4));
#pragma unroll
    for (int j = 0; j < 4; j++)
      b[j] = *(const bf16x8*)(Bs + ((wc + (j << 4) + lan) << 6) + (quad << 4));
#pragma unroll
    for (int i = 0; i < 4; i++)
#pragma unroll
      for (int j = 0; j < 4; j++)
        acc[i][j] = MFMA(a[i], b[j], acc[i][j]);
    __syncthreads();
  }

  float bv[4];
#pragma unroll
  for (int j = 0; j < 4; j++) bv[j] = bias[bn + wc + (j << 4) + lan];
#pragma unroll
  for (int i = 0; i < 4; i++) {
#pragma unroll
    for (int e = 0; e < 4; e++) {
      long row = bm + wr + (i << 4) + (quad << 2) + e;
#pragma unroll
      for (int j = 0; j < 4; j++) {
        float v = acc[i][j][e] + bv[j];
        long col = bn + wc + (j << 4) + lan;
        if (OUT_F32)
          ((float*)Cout)[row * N + col] = v;
        else
          ((__hip_bfloat16*)Cout)[row * N + col] = __float2bfloat16(v);
      }
    }
  }
}

// ---------------------------------------------------------------- flash attention (S^T form)
// QKV: [token][6144] (Q cols 0..4095, K 4096..5119), VT: [(b*8+kvh)][128][2048]
// Ctx: [token][4096]. grid (16, 32, 2) = (q-tiles of 128, QH, B), 256 thr.
// Computes S^T = K·Q^T so softmax reduces in-lane + 2 shfl; O accumulated as O^T.
__global__ void __launch_bounds__(256, 2) flash_attn(const __hip_bfloat16* __restrict__ QKV,
                                                     const __hip_bfloat16* __restrict__ VT,
                                                     __hip_bfloat16* __restrict__ Ctx, int S) {
  __shared__ __align__(16) char smem[50176];
  char* Ks = smem;          // 16KB loop: K tile [64][256B] swizzled; preload: Q rows 0..63
  char* Vs = smem + 16384;  // 16KB loop: V^T tile [128][128B] swizzled; preload: Q rows 64..127
  char* Ps = smem + 32768;  // 17408B: P, 8 strips x (16 rows x 136B)
  const int t = threadIdx.x, w = t >> 6, l = t & 63, quad = l >> 4, lan = l & 15;
  const int b = blockIdx.z, qh = blockIdx.y, kvh = qh >> 2;
  const int q0idx = (int)gridDim.x - 1 - blockIdx.x;  // heavy blocks dispatch first
  const int q0 = q0idx << 7;
  const float cl = 0.08838834764831845f * 1.4426950408889634f;  // 1/sqrt(128) * log2(e)

  // ---- preload 128-row Q tile into smem[0..32767], chunk-swizzled (c ^ row&15)
  {
    int rl = l >> 4, cd = l & 15;
#pragma unroll
    for (int ii = 0; ii < 8; ii++) {
      int i = (w << 3) + ii;
      int r = (i << 2) + rl;
      int cs = cd ^ (r & 15);
      const char* g =
          (const char*)(QKV + (long)(b * S + q0 + r) * 6144 + qh * 128) + (cs << 4);
      g2lds16(g, smem + (i << 10));
    }
  }
  __syncthreads();
  // Q fragments (B-operand): strip = 2w+st, row = strip*16+lan, row&15 == lan
  bf16x8 qf[2][4];
#pragma unroll
  for (int st = 0; st < 2; st++) {
    int row = ((((w << 1) + st) << 4) + lan);
#pragma unroll
    for (int ks = 0; ks < 4; ks++)
      qf[st][ks] = *(const bf16x8*)(smem + (row << 8) + ((((ks << 2) + quad) ^ lan) << 4));
  }

  f32x4 o[2][8] = {};
  float m0[2] = {-__builtin_inff(), -__builtin_inff()};
  float lsum[2] = {0.f, 0.f};
  const int ntiles = (q0idx << 1) + 2;

  for (int kt = 0; kt < ntiles; kt++) {
    const int t0 = kt << 6;
    __syncthreads();  // prior-iter LDS reads (and qf preload reads) done
    // stage K tile [64 rows][256B], swizzled
    {
      int rl = l >> 4, cd = l & 15;
#pragma unroll
      for (int ii = 0; ii < 4; ii++) {
        int i = (w << 2) + ii;
        int r = (i << 2) + rl;
        int cs = cd ^ (r & 15);
        const char* g =
            (const char*)(QKV + (long)(b * S + t0 + r) * 6144 + 4096 + kvh * 128) + (cs << 4);
        g2lds16(g, Ks + (i << 10));
      }
      // stage V^T tile [128 rows][128B], swizzled (c ^ d&7)
      int dl = l >> 3, cd2 = l & 7;
#pragma unroll
      for (int ii = 0; ii < 4; ii++) {
        int i = (w << 2) + ii;
        int d = (i << 3) + dl;
        int cs = cd2 ^ dl;
        const char* g =
            (const char*)(VT + ((long)((b << 3) + kvh) * 128 + d) * S + t0) + (cs << 4);
        g2lds16(g, Vs + (i << 10));
      }
    }
    __syncthreads();

    // S^T[t][q] = K·Q^T : 4 j-tiles (t), each K frag feeds both strips
    f32x4 sa[2][4] = {{}, {}};
#pragma unroll
    for (int j = 0; j < 4; j++)
#pragma unroll
      for (int ks = 0; ks < 4; ks++) {
        bf16x8 kf = *(const bf16x8*)(Ks + (((j << 4) + lan) << 8) +
                                     ((((ks << 2) + quad) ^ lan) << 4));
        sa[0][j] = MFMA(kf, qf[0][ks], sa[0][j]);
        sa[1][j] = MFMA(kf, qf[1][ks], sa[1][j]);
      }

#pragma unroll
    for (int st = 0; st < 2; st++) {
      const int strip = (w << 1) + st;
      const int qg = q0 + (strip << 4) + lan;  // this lane's q row (C/D col = lan)
      if (t0 + 63 > q0 + (strip << 4)) {       // causal mask needed on this tile
#pragma unroll
        for (int j = 0; j < 4; j++)
#pragma unroll
          for (int e = 0; e < 4; e++)
            if (t0 + (j << 4) + (quad << 2) + e > qg) sa[st][j][e] = -1e30f;
      }
      // max over t: in-lane (16 vals) + 2 shfl across quads
      float mq = sa[st][0][0];
#pragma unroll
      for (int j = 0; j < 4; j++)
#pragma unroll
        for (int e = 0; e < 4; e++) mq = fmaxf(mq, sa[st][j][e]);
      mq = fmaxf(mq, __shfl_xor(mq, 16));
      mq = fmaxf(mq, __shfl_xor(mq, 32));
      float mn = fmaxf(m0[st], mq);
      float al = exp2f((m0[st] - mn) * cl);
      m0[st] = mn;
      float rs = 0.f;
      char* prow = Ps + strip * 2176 + lan * 136;
#pragma unroll
      for (int j = 0; j < 4; j++) {
        float p0 = exp2f((sa[st][j][0] - mn) * cl);
        float p1 = exp2f((sa[st][j][1] - mn) * cl);
        float p2 = exp2f((sa[st][j][2] - mn) * cl);
        float p3 = exp2f((sa[st][j][3] - mn) * cl);
        rs += (p0 + p1) + (p2 + p3);
        ushort4 u;
        u.x = bfbits(p0); u.y = bfbits(p1); u.z = bfbits(p2); u.w = bfbits(p3);
        *(ushort4*)(prow + (j << 5) + (quad << 3)) = u;  // P[q=lan][t=j*16+quad*4..+3]
      }
      rs += __shfl_xor(rs, 16);
      rs += __shfl_xor(rs, 32);
      lsum[st] = lsum[st] * al + rs;
#pragma unroll
      for (int dt = 0; dt < 8; dt++) o[st][dt] *= al;
    }

    // O^T += V^T · P^T : same-wave LDS write->read (DS ops in-order per wave)
    bf16x8 pf[2][2];
#pragma unroll
    for (int st = 0; st < 2; st++) {
      char* prow = Ps + ((w << 1) + st) * 2176 + lan * 136;
      pf[st][0] = *(const bf16x8*)(prow + (quad << 4));
      pf[st][1] = *(const bf16x8*)(prow + 64 + (quad << 4));
    }
#pragma unroll
    for (int dt = 0; dt < 8; dt++) {
      const int drow = (dt << 4) + lan;
#pragma unroll
      for (int ks = 0; ks < 2; ks++) {
        bf16x8 vf = *(const bf16x8*)(Vs + (drow << 7) +
                                     ((((ks << 2) + quad) ^ (lan & 7)) << 4));
        o[0][dt] = MFMA(vf, pf[0][ks], o[0][dt]);
        o[1][dt] = MFMA(vf, pf[1][ks], o[1][dt]);
      }
    }
  }

  // epilogue: O^T lane holds q = strip*16+lan, d = dt*16+quad*4+e -> packed 8B stores
#pragma unroll
  for (int st = 0; st < 2; st++) {
    float inv = 1.0f / lsum[st];
    int strip = (w << 1) + st;
    long token = (long)b * S + q0 + (strip << 4) + lan;
    __hip_bfloat16* obase = Ctx + token * 4096 + qh * 128;
#pragma unroll
    for (int dt = 0; dt < 8; dt++) {
      ushort4 u;
      u.x = bfbits(o[st][dt][0] * inv);
      u.y = bfbits(o[st][dt][1] * inv);
      u.z = bfbits(o[st][dt][2] * inv);
      u.w = bfbits(o[st][dt][3] * inv);
      *(ushort4*)(obase + (dt << 4) + (quad << 2)) = u;
    }
  }
}

// ---------------------------------------------------------------- launch
extern "C" void kernel_launch(void* const* d_in, const int* in_sizes, int n_in,
                              void* d_out, int out_size, void* d_ws, size_t ws_size,
                              hipStream_t stream) {
  const float* xs = (const float*)d_in[0];
  const int* startpos = (const int*)d_in[1];
  const float* fc = (const float*)d_in[2];
  const float* Wq = (const float*)d_in[3];
  const float* bq = (const float*)d_in[4];
  const float* Wk = (const float*)d_in[5];
  const float* bk = (const float*)d_in[6];
  const float* Wv = (const float*)d_in[7];
  const float* bv = (const float*)d_in[8];
  const float* Wo = (const float*)d_in[9];
  const float* bo = (const float*)d_in[10];
  float* out = (float*)d_out;
  char* ws = (char*)d_ws;

  __hip_bfloat16* Wqkvb = (__hip_bfloat16*)(ws);               // 48MB [6144][4096]
  __hip_bfloat16* Xb    = (__hip_bfloat16*)(ws + 50331648L);   // 32MB [4096][4096]
  __hip_bfloat16* QKVb  = (__hip_bfloat16*)(ws + 83886080L);   // 48MB [4096][6144]
  __hip_bfloat16* VbT   = (__hip_bfloat16*)(ws + 134217728L);  // 8MB  [16][128][2048]
  float*          bqkv  = (float*)(ws + 142606336L);           // 24KB
  __hip_bfloat16* Wob   = Wqkvb;  // reused after QKV GEMM
  __hip_bfloat16* Ctx   = Xb;     // reused after QKV GEMM

  cvt_f32_bf16<<<16384, 256, 0, stream>>>(xs, Xb, 4194304);
  cvt_f32_bf16<<<16384, 256, 0, stream>>>(Wq, Wqkvb, 4194304);
  cvt_f32_bf16<<<4096, 256, 0, stream>>>(Wk, Wqkvb + 16777216L, 1048576);
  cvt_f32_bf16<<<4096, 256, 0, stream>>>(Wv, Wqkvb + 20971520L, 1048576);
  concat_bias<<<24, 256, 0, stream>>>(bq, bk, bv, bqkv);

  gemm_bt<0><<<dim3(48, 32), 256, 0, stream>>>(Xb, Wqkvb, bqkv, QKVb, 4096, 6144, 4096);

  rope_inplace<<<32768, 256, 0, stream>>>(QKVb, fc, startpos, 6144, 11, 8388608L);
  rope_inplace<<<8192, 256, 0, stream>>>(QKVb + 4096, fc, startpos, 6144, 9, 2097152L);
  transpose_v<<<dim3(64, 4, 16), dim3(32, 8), 0, stream>>>(QKVb, VbT);
  cvt_f32_bf16<<<16384, 256, 0, stream>>>(Wo, Wob, 4194304);  // after QKV GEMM: aliases Wqkvb

  flash_attn<<<dim3(16, 32, 2), 256, 0, stream>>>(QKVb, VbT, Ctx, 2048);

  gemm_bt<1><<<dim3(32, 32), 256, 0, stream>>>(Ctx, Wob, bo, out, 4096, 4096, 4096);
}